// Round 15
// baseline (2077.128 us; speedup 1.0000x reference)
//
#include <hip/hip_runtime.h>
#include <hip/hip_bf16.h>

// problem sizes
constexpr int Bz = 2, IMG = 512, Pp = 16, D = 384, E = 768, S = 16, L = 12;
constexpr int G = IMG / Pp;          // 32
constexpr int Np = G * G;            // 1024 patches
constexpr int M = Bz * Np;           // 2048 rows
constexpr int TWO_E = 2 * E;         // 1536

typedef short bf16x8 __attribute__((ext_vector_type(8)));
typedef float fx4    __attribute__((ext_vector_type(4)));

static __device__ __forceinline__ unsigned short f2bf(float f){
  unsigned int u = __float_as_uint(f);
  u = (u + 0x7FFFu + ((u >> 16) & 1u)) >> 16;       // RN-even
  return (unsigned short)u;
}
static __device__ __forceinline__ float bf2f(unsigned short h){
  return __uint_as_float(((unsigned int)h) << 16);
}

// DPP row-rotate add: sums 16-lane rows without LDS
template<int N>
static __device__ __forceinline__ float ror_add(float v){
  int x = __builtin_amdgcn_update_dpp(0, __float_as_int(v), 0x120 | N, 0xF, 0xF, true);
  return v + __int_as_float(x);
}
static __device__ __forceinline__ float row_sum16(float v){
  v = ror_add<8>(v); v = ror_add<4>(v); v = ror_add<2>(v); v = ror_add<1>(v);
  return v;
}

// ---------------- converted-weight store (device globals) ----------------
constexpr size_t PW_N = (size_t)D * 768;
constexpr size_t IW_N = (size_t)L * TWO_E * D;
constexpr size_t OW_N = (size_t)L * D * E;
constexpr size_t SW_N = (size_t)3 * D * D;
__device__ short g_pw_h[PW_N], g_pw_l[PW_N];
__device__ short g_iw_h[IW_N], g_iw_l[IW_N];
__device__ short g_ow_h[OW_N], g_ow_l[OW_N];
__device__ short g_swx_h[SW_N], g_swx_l[SW_N];

__global__ void convw_kernel(const float* __restrict__ pw, const float* __restrict__ iw,
                             const float* __restrict__ ow, const float* __restrict__ sw){
  size_t i = (size_t)blockIdx.x * 256 + threadIdx.x;
  if (i >= PW_N + IW_N + OW_N + SW_N) return;
  const float* src; short *dh, *dl; size_t j = i;
  if (j < PW_N){ src = pw; dh = g_pw_h; dl = g_pw_l; }
  else if ((j -= PW_N) < IW_N){ src = iw; dh = g_iw_h; dl = g_iw_l; }
  else if ((j -= IW_N) < OW_N){ src = ow; dh = g_ow_h; dl = g_ow_l; }
  else { j -= OW_N; src = sw; dh = g_swx_h; dl = g_swx_l; }
  float f = src[j];
  unsigned short h = f2bf(f);
  dh[j] = (short)h; dl[j] = (short)f2bf(f - bf2f(h));
}

// ---------------- patchify: pixels(f32) -> hi/lo bf16 (M x 768) ----------------
__global__ void patchify_kernel(const float* __restrict__ px,
                                short* __restrict__ oh, short* __restrict__ ol){
  int idx = blockIdx.x * 256 + threadIdx.x;
  if (idx >= M * 768) return;
  int k = idx % 768, m = idx / 768;
  int b = m / Np, n = m % Np;
  int gy = n / G, gx = n % G;
  int c = k / (Pp * Pp), r = k % (Pp * Pp);
  int py = r / Pp, pxi = r % Pp;
  size_t src = ((size_t)(b * 3 + c) * IMG + gy * Pp + py) * IMG + gx * Pp + pxi;
  float f = px[src];
  unsigned short h = f2bf(f);
  oh[idx] = (short)h; ol[idx] = (short)f2bf(f - bf2f(h));
}

// ---------------- layernorm D=384: f32 in -> hi/lo bf16 out ----------------
__global__ __launch_bounds__(256)
void layernorm_bf(const float* __restrict__ x, const float* __restrict__ w,
                  const float* __restrict__ bb, short* __restrict__ oh,
                  short* __restrict__ ol){
  int wave = threadIdx.x >> 6, lane = threadIdx.x & 63;
  int row = blockIdx.x * 4 + wave;
  const float* xr = x + (size_t)row * D;
  float v[6], s = 0.f, sq = 0.f;
  #pragma unroll
  for (int i = 0; i < 6; i++){ v[i] = xr[lane + 64 * i]; s += v[i]; sq += v[i] * v[i]; }
  #pragma unroll
  for (int off = 32; off; off >>= 1){ s += __shfl_xor(s, off); sq += __shfl_xor(sq, off); }
  float mean = s * (1.f / D);
  float var  = sq * (1.f / D) - mean * mean;
  float inv  = 1.0f / sqrtf(var + 1e-5f);
  #pragma unroll
  for (int i = 0; i < 6; i++){
    int c = lane + 64 * i;
    float o = (v[i] - mean) * inv * w[c] + bb[c];
    unsigned short h = f2bf(o);
    oh[(size_t)row * D + c] = (short)h;
    ol[(size_t)row * D + c] = (short)f2bf(o - bf2f(h));
  }
}

// ---------------- final layernorm: f32 -> f32 ----------------
__global__ __launch_bounds__(256)
void layernorm_f32(const float* __restrict__ x, const float* __restrict__ w,
                   const float* __restrict__ bb, float* __restrict__ outf){
  int wave = threadIdx.x >> 6, lane = threadIdx.x & 63;
  int row = blockIdx.x * 4 + wave;
  const float* xr = x + (size_t)row * D;
  float v[6], s = 0.f, sq = 0.f;
  #pragma unroll
  for (int i = 0; i < 6; i++){ v[i] = xr[lane + 64 * i]; s += v[i]; sq += v[i] * v[i]; }
  #pragma unroll
  for (int off = 32; off; off >>= 1){ s += __shfl_xor(s, off); sq += __shfl_xor(sq, off); }
  float mean = s * (1.f / D);
  float var  = sq * (1.f / D) - mean * mean;
  float inv  = 1.0f / sqrtf(var + 1e-5f);
  #pragma unroll
  for (int i = 0; i < 6; i++){
    int c = lane + 64 * i;
    outf[(size_t)row * D + c] = (v[i] - mean) * inv * w[c] + bb[c];
  }
}

// ---------------- in-proj MFMA GEMM, BM=64 x BN=128 (384 blocks) ----------------
// 4 waves; wave computes 64m x 32n. Split epilogue: xmT / silu(z) transposed.
__global__ __launch_bounds__(256)
void gemm_in(const short* __restrict__ Ah, const short* __restrict__ Al,
             size_t woff, const float* __restrict__ bias,
             float* __restrict__ C, float* __restrict__ C2){
  constexpr int BKp = 40;
  __shared__ __align__(16) short sAh[64 * BKp],  sAl[64 * BKp];
  __shared__ __align__(16) short sWh[128 * BKp], sWl[128 * BKp];
  const short* Wh = g_iw_h + woff;
  const short* Wl = g_iw_l + woff;
  const int t = threadIdx.x, wid = t >> 6, lane = t & 63;
  const int m0 = blockIdx.y * 64, n0 = blockIdx.x * 128;
  const int wn = wid * 32;

  fx4 acc[4][2];
  #pragma unroll
  for (int a = 0; a < 4; a++)
    #pragma unroll
    for (int b = 0; b < 2; b++)
      #pragma unroll
      for (int i = 0; i < 4; i++) acc[a][b][i] = 0.f;

  const int rA = t >> 2, kpA = (t & 3) << 3;    // A: 64 rows x 4 chunks
  const int rW = t >> 1, kpW = (t & 1) << 4;    // W: 128 rows x 2 half-rows
  const int row = lane & 15, kq = lane >> 4;

  for (int kt = 0; kt < D; kt += 32){
    *(bf16x8*)&sAh[rA * BKp + kpA] = *(const bf16x8*)(Ah + (size_t)(m0 + rA) * D + kt + kpA);
    *(bf16x8*)&sAl[rA * BKp + kpA] = *(const bf16x8*)(Al + (size_t)(m0 + rA) * D + kt + kpA);
    *(bf16x8*)&sWh[rW * BKp + kpW]     = *(const bf16x8*)(Wh + (size_t)(n0 + rW) * D + kt + kpW);
    *(bf16x8*)&sWh[rW * BKp + kpW + 8] = *(const bf16x8*)(Wh + (size_t)(n0 + rW) * D + kt + kpW + 8);
    *(bf16x8*)&sWl[rW * BKp + kpW]     = *(const bf16x8*)(Wl + (size_t)(n0 + rW) * D + kt + kpW);
    *(bf16x8*)&sWl[rW * BKp + kpW + 8] = *(const bf16x8*)(Wl + (size_t)(n0 + rW) * D + kt + kpW + 8);
    __syncthreads();
    bf16x8 ah[4], al[4], bh[2], bl[2];
    #pragma unroll
    for (int tm = 0; tm < 4; tm++){
      ah[tm] = *(const bf16x8*)&sAh[(tm * 16 + row) * BKp + kq * 8];
      al[tm] = *(const bf16x8*)&sAl[(tm * 16 + row) * BKp + kq * 8];
    }
    #pragma unroll
    for (int tn = 0; tn < 2; tn++){
      bh[tn] = *(const bf16x8*)&sWh[(wn + tn * 16 + row) * BKp + kq * 8];
      bl[tn] = *(const bf16x8*)&sWl[(wn + tn * 16 + row) * BKp + kq * 8];
    }
    #pragma unroll
    for (int tm = 0; tm < 4; tm++)
      #pragma unroll
      for (int tn = 0; tn < 2; tn++){
        acc[tm][tn] = __builtin_amdgcn_mfma_f32_16x16x32_bf16(ah[tm], bh[tn], acc[tm][tn], 0, 0, 0);
        acc[tm][tn] = __builtin_amdgcn_mfma_f32_16x16x32_bf16(ah[tm], bl[tn], acc[tm][tn], 0, 0, 0);
        acc[tm][tn] = __builtin_amdgcn_mfma_f32_16x16x32_bf16(al[tm], bh[tn], acc[tm][tn], 0, 0, 0);
      }
    __syncthreads();
  }

  const int row4 = (lane >> 4) * 4, coln = lane & 15;
  #pragma unroll
  for (int tm = 0; tm < 4; tm++)
    #pragma unroll
    for (int tn = 0; tn < 2; tn++){
      int n = n0 + wn + tn * 16 + coln;
      int mb = m0 + tm * 16 + row4;
      float4 v4;
      float* vp = (float*)&v4;
      #pragma unroll
      for (int i = 0; i < 4; i++) vp[i] = acc[tm][tn][i] + bias[n];
      if (n < E){
        *(float4*)&C[(size_t)n * M + mb] = v4;          // xmT transposed
      } else {
        #pragma unroll
        for (int i = 0; i < 4; i++){
          float sig = 1.f / (1.f + expf(-vp[i]));
          vp[i] = vp[i] * sig;
        }
        *(float4*)&C2[(size_t)(n - E) * M + mb] = v4;   // zst transposed
      }
    }
}

// ---------------- patch MFMA GEMM 64x64 (pre-split A, +pos epilogue) ----------------
__global__ __launch_bounds__(256)
void gemm_patch(const short* __restrict__ Ah, const short* __restrict__ Al,
                const float* __restrict__ bias, float* __restrict__ C,
                const float* __restrict__ pos){
  constexpr int BKp = 40;
  __shared__ __align__(16) short sAh[64 * BKp], sAl[64 * BKp];
  __shared__ __align__(16) short sWh[64 * BKp], sWl[64 * BKp];
  const int t = threadIdx.x, wid = t >> 6, lane = t & 63;
  const int m0 = blockIdx.y * 64, n0 = blockIdx.x * 64;

  fx4 acc[4];
  #pragma unroll
  for (int a = 0; a < 4; a++)
    #pragma unroll
    for (int i = 0; i < 4; i++) acc[a][i] = 0.f;

  const int r = t >> 2, kp = (t & 3) << 3;
  const int row = lane & 15, kq = lane >> 4;

  for (int kt = 0; kt < 768; kt += 32){
    *(bf16x8*)&sAh[r * BKp + kp] = *(const bf16x8*)(Ah + (size_t)(m0 + r) * 768 + kt + kp);
    *(bf16x8*)&sAl[r * BKp + kp] = *(const bf16x8*)(Al + (size_t)(m0 + r) * 768 + kt + kp);
    *(bf16x8*)&sWh[r * BKp + kp] = *(const bf16x8*)(g_pw_h + (size_t)(n0 + r) * 768 + kt + kp);
    *(bf16x8*)&sWl[r * BKp + kp] = *(const bf16x8*)(g_pw_l + (size_t)(n0 + r) * 768 + kt + kp);
    __syncthreads();
    bf16x8 bh = *(const bf16x8*)&sWh[(wid * 16 + row) * BKp + kq * 8];
    bf16x8 bl = *(const bf16x8*)&sWl[(wid * 16 + row) * BKp + kq * 8];
    #pragma unroll
    for (int tm = 0; tm < 4; tm++){
      bf16x8 ah = *(const bf16x8*)&sAh[(tm * 16 + row) * BKp + kq * 8];
      bf16x8 al = *(const bf16x8*)&sAl[(tm * 16 + row) * BKp + kq * 8];
      acc[tm] = __builtin_amdgcn_mfma_f32_16x16x32_bf16(ah, bh, acc[tm], 0, 0, 0);
      acc[tm] = __builtin_amdgcn_mfma_f32_16x16x32_bf16(ah, bl, acc[tm], 0, 0, 0);
      acc[tm] = __builtin_amdgcn_mfma_f32_16x16x32_bf16(al, bh, acc[tm], 0, 0, 0);
    }
    __syncthreads();
  }

  const int row4 = (lane >> 4) * 4, coln = lane & 15;
  #pragma unroll
  for (int tm = 0; tm < 4; tm++){
    int n = n0 + wid * 16 + coln;
    int mb = m0 + tm * 16 + row4;
    #pragma unroll
    for (int i = 0; i < 4; i++){
      int m = mb + i;
      C[(size_t)m * D + n] = acc[tm][i] + bias[n] + pos[(size_t)(m & (Np - 1)) * D + n];
    }
  }
}

// ---------------- scale MFMA GEMM 64x64: A = f32 x, hi/lo converted in staging ----------------
__global__ __launch_bounds__(256)
void gemm_scale(const float* __restrict__ A, size_t woff,
                const float* __restrict__ bias, float* __restrict__ C){
  constexpr int BKp = 40;
  __shared__ __align__(16) short sAh[64 * BKp], sAl[64 * BKp];
  __shared__ __align__(16) short sWh[64 * BKp], sWl[64 * BKp];
  const short* Wh = g_swx_h + woff;
  const short* Wl = g_swx_l + woff;
  const int t = threadIdx.x, wid = t >> 6, lane = t & 63;
  const int m0 = blockIdx.y * 64, n0 = blockIdx.x * 64;

  fx4 acc[4];
  #pragma unroll
  for (int a = 0; a < 4; a++)
    #pragma unroll
    for (int i = 0; i < 4; i++) acc[a][i] = 0.f;

  const int r = t >> 2, kp = (t & 3) << 3;
  const int row = lane & 15, kq = lane >> 4;

  for (int kt = 0; kt < D; kt += 32){
    { // A staging: 8 f32 -> hi/lo bf16
      const float* ap = A + (size_t)(m0 + r) * D + kt + kp;
      float4 f0 = *(const float4*)ap, f1 = *(const float4*)(ap + 4);
      float f[8] = {f0.x, f0.y, f0.z, f0.w, f1.x, f1.y, f1.z, f1.w};
      short hh[8], ll[8];
      #pragma unroll
      for (int i = 0; i < 8; i++){
        unsigned short h = f2bf(f[i]);
        hh[i] = (short)h; ll[i] = (short)f2bf(f[i] - bf2f(h));
      }
      *(bf16x8*)&sAh[r * BKp + kp] = *(bf16x8*)hh;
      *(bf16x8*)&sAl[r * BKp + kp] = *(bf16x8*)ll;
    }
    *(bf16x8*)&sWh[r * BKp + kp] = *(const bf16x8*)(Wh + (size_t)(n0 + r) * D + kt + kp);
    *(bf16x8*)&sWl[r * BKp + kp] = *(const bf16x8*)(Wl + (size_t)(n0 + r) * D + kt + kp);
    __syncthreads();
    bf16x8 bh = *(const bf16x8*)&sWh[(wid * 16 + row) * BKp + kq * 8];
    bf16x8 bl = *(const bf16x8*)&sWl[(wid * 16 + row) * BKp + kq * 8];
    #pragma unroll
    for (int tm = 0; tm < 4; tm++){
      bf16x8 ah = *(const bf16x8*)&sAh[(tm * 16 + row) * BKp + kq * 8];
      bf16x8 al = *(const bf16x8*)&sAl[(tm * 16 + row) * BKp + kq * 8];
      acc[tm] = __builtin_amdgcn_mfma_f32_16x16x32_bf16(ah, bh, acc[tm], 0, 0, 0);
      acc[tm] = __builtin_amdgcn_mfma_f32_16x16x32_bf16(ah, bl, acc[tm], 0, 0, 0);
      acc[tm] = __builtin_amdgcn_mfma_f32_16x16x32_bf16(al, bh, acc[tm], 0, 0, 0);
    }
    __syncthreads();
  }

  const int row4 = (lane >> 4) * 4, coln = lane & 15;
  #pragma unroll
  for (int tm = 0; tm < 4; tm++){
    int n = n0 + wid * 16 + coln;
    int mb = m0 + tm * 16 + row4;
    #pragma unroll
    for (int i = 0; i < 4; i++){
      int m = mb + i;
      C[(size_t)m * D + n] = acc[tm][i] + bias[n];
    }
  }
}

// ---------------- out-proj MFMA GEMM, TRANSPOSED A; epilogue: residual add + zero xBC ----------------
__global__ __launch_bounds__(256)
void gemm_bf_at(const short* __restrict__ ATh, const short* __restrict__ ATl, int K,
                size_t woff, const float* __restrict__ bias,
                float* __restrict__ C, int ncols, float* __restrict__ zbuf){
  constexpr int BKp = 40;
  __shared__ __align__(16) short sAh[64 * BKp], sAl[64 * BKp];
  __shared__ __align__(16) short sWh[64 * BKp], sWl[64 * BKp];
  const short* Wh = g_ow_h + woff;
  const short* Wl = g_ow_l + woff;
  const int t = threadIdx.x, wid = t >> 6, lane = t & 63;
  const int m0 = blockIdx.y * 64, n0 = blockIdx.x * 64;

  fx4 acc[4];
  #pragma unroll
  for (int a = 0; a < 4; a++)
    #pragma unroll
    for (int i = 0; i < 4; i++) acc[a][i] = 0.f;

  const int rw = t >> 2, kpw = (t & 3) << 3;
  const int kr2 = (t & 15) * 2, mc4 = (t >> 4) * 4;
  const int row = lane & 15, kq = lane >> 4;

  for (int kt = 0; kt < K; kt += 32){
    {
      const uint2 h0 = *(const uint2*)(ATh + (size_t)(kt + kr2) * M + m0 + mc4);
      const uint2 h1 = *(const uint2*)(ATh + (size_t)(kt + kr2 + 1) * M + m0 + mc4);
      const uint2 l0 = *(const uint2*)(ATl + (size_t)(kt + kr2) * M + m0 + mc4);
      const uint2 l1 = *(const uint2*)(ATl + (size_t)(kt + kr2 + 1) * M + m0 + mc4);
      const unsigned int h0a[2] = {h0.x, h0.y}, h1a[2] = {h1.x, h1.y};
      const unsigned int l0a[2] = {l0.x, l0.y}, l1a[2] = {l1.x, l1.y};
      #pragma unroll
      for (int j = 0; j < 4; j++){
        unsigned int s0 = (h0a[j >> 1] >> ((j & 1) * 16)) & 0xFFFFu;
        unsigned int s1 = (h1a[j >> 1] >> ((j & 1) * 16)) & 0xFFFFu;
        *(unsigned int*)&sAh[(mc4 + j) * BKp + kr2] = s0 | (s1 << 16);
        unsigned int t0 = (l0a[j >> 1] >> ((j & 1) * 16)) & 0xFFFFu;
        unsigned int t1 = (l1a[j >> 1] >> ((j & 1) * 16)) & 0xFFFFu;
        *(unsigned int*)&sAl[(mc4 + j) * BKp + kr2] = t0 | (t1 << 16);
      }
    }
    *(bf16x8*)&sWh[rw * BKp + kpw] = *(const bf16x8*)(Wh + (size_t)(n0 + rw) * K + kt + kpw);
    *(bf16x8*)&sWl[rw * BKp + kpw] = *(const bf16x8*)(Wl + (size_t)(n0 + rw) * K + kt + kpw);
    __syncthreads();
    bf16x8 bh = *(const bf16x8*)&sWh[(wid * 16 + row) * BKp + kq * 8];
    bf16x8 bl = *(const bf16x8*)&sWl[(wid * 16 + row) * BKp + kq * 8];
    #pragma unroll
    for (int tm = 0; tm < 4; tm++){
      bf16x8 ah = *(const bf16x8*)&sAh[(tm * 16 + row) * BKp + kq * 8];
      bf16x8 al = *(const bf16x8*)&sAl[(tm * 16 + row) * BKp + kq * 8];
      acc[tm] = __builtin_amdgcn_mfma_f32_16x16x32_bf16(ah, bh, acc[tm], 0, 0, 0);
      acc[tm] = __builtin_amdgcn_mfma_f32_16x16x32_bf16(ah, bl, acc[tm], 0, 0, 0);
      acc[tm] = __builtin_amdgcn_mfma_f32_16x16x32_bf16(al, bh, acc[tm], 0, 0, 0);
    }
    __syncthreads();
  }

  const int row4 = (lane >> 4) * 4, coln = lane & 15;
  #pragma unroll
  for (int tm = 0; tm < 4; tm++)
    #pragma unroll
    for (int i = 0; i < 4; i++){
      int m = m0 + tm * 16 + row4 + i;
      int n = n0 + wid * 16 + coln;
      float v = acc[tm][i] + bias[n] + C[(size_t)m * ncols + n];
      C[(size_t)m * ncols + n] = v;
    }

  // zero xBC for next layer's xp accumulation (not read by this kernel; stream order
  // guarantees next layer's gemm_xp sees zeros)
  int gid = blockIdx.y * gridDim.x + blockIdx.x;
  int idx = gid * 256 + t;
  if (idx < M * 16)                      // M*32 floats as float2
    *(float2*)&zbuf[idx * 2] = make_float2(0.f, 0.f);
}

// ---------------- xp GEMM (K-split x4, atomic): xBC packed [m][(xB,xC) pairs] ----------------
__global__ __launch_bounds__(256)
void gemm_xp(const float* __restrict__ xcT, const float* __restrict__ W,
             const float* __restrict__ bias, float* __restrict__ C){
  __shared__ float As[16][64 + 1];
  __shared__ float Ws[16][32 + 1];
  int tid = threadIdx.x;
  int tx = tid & 15, ty = tid >> 4;
  int m0 = blockIdx.y * 64, kb = blockIdx.x * 192;
  float acc[4][2];
  #pragma unroll
  for (int i = 0; i < 4; i++){ acc[i][0] = 0.f; acc[i][1] = 0.f; }
  for (int kt = kb; kt < kb + 192; kt += 16){
    #pragma unroll
    for (int ps = 0; ps < 4; ps++){
      int rr = (tid >> 6) + 4 * ps, mc = tid & 63;
      As[rr][mc] = xcT[(size_t)(kt + rr) * M + m0 + mc];
    }
    if (tid < 128){
      int c = tid >> 2, kk = (tid & 3) << 2;
      const float* wp = W + (size_t)c * E + kt + kk;
      Ws[kk + 0][c] = wp[0]; Ws[kk + 1][c] = wp[1];
      Ws[kk + 2][c] = wp[2]; Ws[kk + 3][c] = wp[3];
    }
    __syncthreads();
    #pragma unroll
    for (int k = 0; k < 16; k++){
      float a[4], w[2];
      #pragma unroll
      for (int i = 0; i < 4; i++) a[i] = As[k][ty * 4 + i];
      w[0] = Ws[k][tx * 2]; w[1] = Ws[k][tx * 2 + 1];
      #pragma unroll
      for (int i = 0; i < 4; i++){ acc[i][0] += a[i] * w[0]; acc[i][1] += a[i] * w[1]; }
    }
    __syncthreads();
  }
  #pragma unroll
  for (int i = 0; i < 4; i++){
    int m = m0 + ty * 4 + i;
    #pragma unroll
    for (int j = 0; j < 2; j++){
      int n = tx * 2 + j;                        // 0..31 original index
      int np = (n & 15) * 2 + (n >> 4);          // packed: (xB,xC) interleaved
      float v = acc[i][j];
      if (blockIdx.x == 0) v += bias[n];
      atomicAdd(&C[(size_t)m * 32 + np], v);
    }
  }
}

// ---------------- depthwise causal conv (K=4) + SiLU on transposed layout ----------------
__global__ __launch_bounds__(256)
void conv_silu_t(const float* __restrict__ xmT, const float* __restrict__ cw,
                 const float* __restrict__ cb, float* __restrict__ xcT){
  const int e = blockIdx.x, t = threadIdx.x;
  const float w0 = cw[e * 4], w1 = cw[e * 4 + 1], w2 = cw[e * 4 + 2], w3 = cw[e * 4 + 3];
  const float bias = cb[e];
  const float* src = xmT + (size_t)e * M;
  float* dst = xcT + (size_t)e * M;
  int mb = t * 8;
  #pragma unroll
  for (int j = 0; j < 8; j++){
    int m = mb + j, n = m & (Np - 1);
    float acc = bias + w3 * src[m];
    if (n >= 1) acc += w2 * src[m - 1];
    if (n >= 2) acc += w1 * src[m - 2];
    if (n >= 3) acc += w0 * src[m - 3];
    float sig = 1.f / (1.f + expf(-acc));
    dst[m] = acc * sig;
  }
}

// ---------------- chunked selective scan: fused dt, packed xBC ----------------
// dt in [1e-4,1], A in [-16,-1] => dt*a in [-16,-1e-4]; ref's [-20,0] clip can't fire.
__global__ __launch_bounds__(256)
void scan_kernel(const float* __restrict__ xcT, const float* __restrict__ zst,
                 const float* __restrict__ xBC,
                 const float* __restrict__ Aptr, const float* __restrict__ Dp,
                 const float* __restrict__ dt_w, const float* __restrict__ dt_b,
                 short* __restrict__ yh, short* __restrict__ yl){
  __shared__ float yloc[16 * 65];
  __shared__ float sdt[64 * 17], sxc[64 * 17];
  __shared__ float hloc[16][16], prodA[16][16], Hin[16][16];
  const int t = threadIdx.x, g = t >> 4, s = t & 15;
  const int r = blockIdx.x, b = r / E, e = r % E;
  const float a   = Aptr[e * S + s];
  const float dpe = Dp[e];
  const float* xcp = xcT + (size_t)e * M + b * Np;
  const float* zsp = zst + (size_t)e * M + b * Np;
  const int bNp = b * Np;

  { // preload: dt from packed xBC (even slots = xB), stage xc
    const float* dw = dt_w + e * 16;
    float w[16];
    #pragma unroll
    for (int i = 0; i < 16; i += 4){
      float4 w4 = *(const float4*)(dw + i);
      w[i] = w4.x; w[i + 1] = w4.y; w[i + 2] = w4.z; w[i + 3] = w4.w;
    }
    float db = dt_b[e];
    #pragma unroll
    for (int q = t; q < 1024; q += 256){
      const float* xb = xBC + (size_t)(bNp + q) * 32;
      float v = db;
      #pragma unroll
      for (int i2 = 0; i2 < 8; i2++){
        float4 p4 = *(const float4*)(xb + 4 * i2);
        v += p4.x * w[2 * i2] + p4.z * w[2 * i2 + 1];
      }
      v = (v > 15.f) ? v : log1pf(expf(v));
      v = fminf(fmaxf(v, 1e-4f), 1.0f);
      sdt[(q & 63) * 17 + (q >> 6)] = v;
      sxc[(q & 63) * 17 + (q >> 6)] = xcp[q];
    }
  }
  __syncthreads();

  const int n0 = g * 64;
  const int mbase = bNp + n0;

  float h = 0.f, P = 1.f;
  #pragma unroll 8
  for (int i = 0; i < 64; i++){
    int m = mbase + i;
    float dt  = sdt[i * 17 + g];
    float xcv = sxc[i * 17 + g];
    float2 bc = *(const float2*)(xBC + (size_t)m * 32 + 2 * s);
    float dA = __expf(dt * a);
    h = dA * h + bc.x * xcv;
    P *= dA;
    float p = row_sum16(h * bc.y);
    if (s == 0) yloc[g * 65 + i] = p + dpe * xcv;
  }
  hloc[g][s] = h; prodA[g][s] = P;
  __syncthreads();
  if (t < 16){
    float H = 0.f;
    #pragma unroll
    for (int g2 = 0; g2 < 16; g2++){
      Hin[g2][t] = H;
      H = prodA[g2][t] * H + hloc[g2][t];
    }
  }
  __syncthreads();
  float Q = Hin[g][s];
  #pragma unroll 8
  for (int i = 0; i < 64; i++){
    int m = mbase + i;
    float dt  = sdt[i * 17 + g];
    float2 bc = *(const float2*)(xBC + (size_t)m * 32 + 2 * s);
    float dA = __expf(dt * a);
    Q *= dA;
    float p = row_sum16(Q * bc.y);
    if (s == 0) yloc[g * 65 + i] += p;
  }
  __syncthreads();

  { // coalesced hi/lo bf16 write, [e][m] layout
    int n4 = t * 4;
    float4 z4 = *(const float4*)&zsp[n4];
    const float* zp = (const float*)&z4;
    int gy = n4 >> 6, iy = n4 & 63;
    unsigned int hpack[2], lpack[2];
    #pragma unroll
    for (int half = 0; half < 2; half++){
      unsigned int hp = 0, lp = 0;
      #pragma unroll
      for (int j = 0; j < 2; j++){
        float val = yloc[gy * 65 + iy + half * 2 + j] * zp[half * 2 + j];
        unsigned short hh = f2bf(val);
        unsigned short ll = f2bf(val - bf2f(hh));
        hp |= ((unsigned int)hh) << (16 * j);
        lp |= ((unsigned int)ll) << (16 * j);
      }
      hpack[half] = hp; lpack[half] = lp;
    }
    size_t o = (size_t)e * M + bNp + n4;
    *(uint2*)&yh[o] = make_uint2(hpack[0], hpack[1]);
    *(uint2*)&yl[o] = make_uint2(lpack[0], lpack[1]);
  }
}

extern "C" void kernel_launch(void* const* d_in, const int* in_sizes, int n_in,
                              void* d_out, int out_size, void* d_ws, size_t ws_size,
                              hipStream_t stream){
  const float* px      = (const float*)d_in[0];
  const float* patch_w = (const float*)d_in[1];
  const float* patch_b = (const float*)d_in[2];
  const float* pos     = (const float*)d_in[3];
  const float* norm_w  = (const float*)d_in[4];
  const float* norm_b  = (const float*)d_in[5];
  const float* in_w    = (const float*)d_in[6];
  const float* in_b    = (const float*)d_in[7];
  const float* conv_w  = (const float*)d_in[8];
  const float* conv_b  = (const float*)d_in[9];
  const float* xp_w    = (const float*)d_in[10];
  const float* xp_b    = (const float*)d_in[11];
  const float* dt_w    = (const float*)d_in[12];
  const float* dt_b    = (const float*)d_in[13];
  const float* Aab     = (const float*)d_in[14];
  const float* Dp      = (const float*)d_in[15];
  const float* out_w   = (const float*)d_in[16];
  const float* out_b   = (const float*)d_in[17];
  const float* fnorm_w = (const float*)d_in[18];
  const float* fnorm_b = (const float*)d_in[19];
  const float* scale_w = (const float*)d_in[20];
  const float* scale_b = (const float*)d_in[21];
  float* out = (float*)d_out;

  // workspace
  float* x   = (float*)d_ws;                  // M*D
  float* xmT = x + (size_t)M * D;             // E*M f32 (transposed x_main)
  float* zst = xmT + (size_t)M * E;           // E*M
  float* xcT = zst + (size_t)M * E;           // E*M
  float* xBC = xcT + (size_t)M * E;           // M*32 (packed (xB,xC) pairs)
  short* xnh = (short*)(xBC + (size_t)M * 32);// M*D
  short* xnl = xnh + (size_t)M * D;           // M*D
  short* yh  = (short*)xmT;                   // E*M shorts (alias: dead x_main)
  short* yl  = yh + (size_t)M * E;
  short* pbh = yh, *pbl = yl;                 // patch buffer alias

  constexpr size_t TOTW = PW_N + IW_N + OW_N + SW_N;
  convw_kernel<<<(int)((TOTW + 255) / 256), 256, 0, stream>>>(patch_w, in_w, out_w, scale_w);
  hipMemsetAsync(xBC, 0, (size_t)M * 32 * sizeof(float), stream);   // layer-0 init

  patchify_kernel<<<(M * 768 + 255) / 256, 256, 0, stream>>>(px, pbh, pbl);
  gemm_patch<<<dim3(D / 64, M / 64), 256, 0, stream>>>(pbh, pbl, patch_b, x, pos);

  for (int l = 0; l < L; l++){
    layernorm_bf<<<M / 4, 256, 0, stream>>>(x, norm_w + l * D, norm_b + l * D, xnh, xnl);
    gemm_in<<<dim3(TWO_E / 128, M / 64), 256, 0, stream>>>(
        xnh, xnl, (size_t)l * TWO_E * D, in_b + l * TWO_E, xmT, zst);
    conv_silu_t<<<E, 256, 0, stream>>>(
        xmT, conv_w + (size_t)l * E * 4, conv_b + l * E, xcT);
    gemm_xp<<<dim3(4, M / 64), 256, 0, stream>>>(
        xcT, xp_w + (size_t)l * 32 * E, xp_b + l * 32, xBC);
    scan_kernel<<<Bz * E, 256, 0, stream>>>(
        xcT, zst, xBC, Aab + (size_t)l * E * S, Dp + l * E,
        dt_w + (size_t)l * E * S, dt_b + l * E, yh, yl);
    gemm_bf_at<<<dim3(D / 64, M / 64), 256, 0, stream>>>(
        yh, yl, E, (size_t)l * D * E, out_b + l * D, x, D, xBC);
    if (l % 4 == 0 && l / 4 < 3){
      int j = l / 4;
      gemm_scale<<<dim3(D / 64, M / 64), 256, 0, stream>>>(
          x, (size_t)j * D * D, scale_b + j * D, out + (size_t)(1 + j) * M * D);
    }
  }
  layernorm_f32<<<M / 4, 256, 0, stream>>>(x, fnorm_w, fnorm_b, out);
}

// Round 16
// 1680.965 us; speedup vs baseline: 1.2357x; 1.2357x over previous
//
#include <hip/hip_runtime.h>
#include <hip/hip_bf16.h>

// problem sizes
constexpr int Bz = 2, IMG = 512, Pp = 16, D = 384, E = 768, S = 16, L = 12;
constexpr int G = IMG / Pp;          // 32
constexpr int Np = G * G;            // 1024 patches
constexpr int M = Bz * Np;           // 2048 rows
constexpr int TWO_E = 2 * E;         // 1536

typedef short bf16x8 __attribute__((ext_vector_type(8)));
typedef float fx4    __attribute__((ext_vector_type(4)));

static __device__ __forceinline__ unsigned short f2bf(float f){
  unsigned int u = __float_as_uint(f);
  u = (u + 0x7FFFu + ((u >> 16) & 1u)) >> 16;       // RN-even
  return (unsigned short)u;
}
static __device__ __forceinline__ float bf2f(unsigned short h){
  return __uint_as_float(((unsigned int)h) << 16);
}

// DPP row-rotate add: sums 16-lane rows without LDS
template<int N>
static __device__ __forceinline__ float ror_add(float v){
  int x = __builtin_amdgcn_update_dpp(0, __float_as_int(v), 0x120 | N, 0xF, 0xF, true);
  return v + __int_as_float(x);
}
static __device__ __forceinline__ float row_sum16(float v){
  v = ror_add<8>(v); v = ror_add<4>(v); v = ror_add<2>(v); v = ror_add<1>(v);
  return v;
}

// ---------------- converted-weight store (device globals) ----------------
constexpr size_t PW_N = (size_t)D * 768;
constexpr size_t IW_N = (size_t)L * TWO_E * D;
constexpr size_t OW_N = (size_t)L * D * E;
constexpr size_t SW_N = (size_t)3 * D * D;
__device__ short g_pw_h[PW_N], g_pw_l[PW_N];
__device__ short g_iw_h[IW_N], g_iw_l[IW_N];
__device__ short g_ow_h[OW_N], g_ow_l[OW_N];
__device__ short g_swx_h[SW_N], g_swx_l[SW_N];

__global__ void convw_kernel(const float* __restrict__ pw, const float* __restrict__ iw,
                             const float* __restrict__ ow, const float* __restrict__ sw){
  size_t i = (size_t)blockIdx.x * 256 + threadIdx.x;
  if (i >= PW_N + IW_N + OW_N + SW_N) return;
  const float* src; short *dh, *dl; size_t j = i;
  if (j < PW_N){ src = pw; dh = g_pw_h; dl = g_pw_l; }
  else if ((j -= PW_N) < IW_N){ src = iw; dh = g_iw_h; dl = g_iw_l; }
  else if ((j -= IW_N) < OW_N){ src = ow; dh = g_ow_h; dl = g_ow_l; }
  else { j -= OW_N; src = sw; dh = g_swx_h; dl = g_swx_l; }
  float f = src[j];
  unsigned short h = f2bf(f);
  dh[j] = (short)h; dl[j] = (short)f2bf(f - bf2f(h));
}

// ---------------- patchify: pixels(f32) -> hi/lo bf16 (M x 768) ----------------
__global__ void patchify_kernel(const float* __restrict__ px,
                                short* __restrict__ oh, short* __restrict__ ol){
  int idx = blockIdx.x * 256 + threadIdx.x;
  if (idx >= M * 768) return;
  int k = idx % 768, m = idx / 768;
  int b = m / Np, n = m % Np;
  int gy = n / G, gx = n % G;
  int c = k / (Pp * Pp), r = k % (Pp * Pp);
  int py = r / Pp, pxi = r % Pp;
  size_t src = ((size_t)(b * 3 + c) * IMG + gy * Pp + py) * IMG + gx * Pp + pxi;
  float f = px[src];
  unsigned short h = f2bf(f);
  oh[idx] = (short)h; ol[idx] = (short)f2bf(f - bf2f(h));
}

// ---------------- layernorm D=384: f32 in -> hi/lo bf16 out ----------------
__global__ __launch_bounds__(256)
void layernorm_bf(const float* __restrict__ x, const float* __restrict__ w,
                  const float* __restrict__ bb, short* __restrict__ oh,
                  short* __restrict__ ol){
  int wave = threadIdx.x >> 6, lane = threadIdx.x & 63;
  int row = blockIdx.x * 4 + wave;
  const float* xr = x + (size_t)row * D;
  float v[6], s = 0.f, sq = 0.f;
  #pragma unroll
  for (int i = 0; i < 6; i++){ v[i] = xr[lane + 64 * i]; s += v[i]; sq += v[i] * v[i]; }
  #pragma unroll
  for (int off = 32; off; off >>= 1){ s += __shfl_xor(s, off); sq += __shfl_xor(sq, off); }
  float mean = s * (1.f / D);
  float var  = sq * (1.f / D) - mean * mean;
  float inv  = 1.0f / sqrtf(var + 1e-5f);
  #pragma unroll
  for (int i = 0; i < 6; i++){
    int c = lane + 64 * i;
    float o = (v[i] - mean) * inv * w[c] + bb[c];
    unsigned short h = f2bf(o);
    oh[(size_t)row * D + c] = (short)h;
    ol[(size_t)row * D + c] = (short)f2bf(o - bf2f(h));
  }
}

// ---------------- final layernorm: f32 -> f32 ----------------
__global__ __launch_bounds__(256)
void layernorm_f32(const float* __restrict__ x, const float* __restrict__ w,
                   const float* __restrict__ bb, float* __restrict__ outf){
  int wave = threadIdx.x >> 6, lane = threadIdx.x & 63;
  int row = blockIdx.x * 4 + wave;
  const float* xr = x + (size_t)row * D;
  float v[6], s = 0.f, sq = 0.f;
  #pragma unroll
  for (int i = 0; i < 6; i++){ v[i] = xr[lane + 64 * i]; s += v[i]; sq += v[i] * v[i]; }
  #pragma unroll
  for (int off = 32; off; off >>= 1){ s += __shfl_xor(s, off); sq += __shfl_xor(sq, off); }
  float mean = s * (1.f / D);
  float var  = sq * (1.f / D) - mean * mean;
  float inv  = 1.0f / sqrtf(var + 1e-5f);
  #pragma unroll
  for (int i = 0; i < 6; i++){
    int c = lane + 64 * i;
    outf[(size_t)row * D + c] = (v[i] - mean) * inv * w[c] + bb[c];
  }
}

// ---------------- in-proj MFMA GEMM, BM=64 x BN=128 (384 blocks) ----------------
__global__ __launch_bounds__(256)
void gemm_in(const short* __restrict__ Ah, const short* __restrict__ Al,
             size_t woff, const float* __restrict__ bias,
             float* __restrict__ C, float* __restrict__ C2){
  constexpr int BKp = 40;
  __shared__ __align__(16) short sAh[64 * BKp],  sAl[64 * BKp];
  __shared__ __align__(16) short sWh[128 * BKp], sWl[128 * BKp];
  const short* Wh = g_iw_h + woff;
  const short* Wl = g_iw_l + woff;
  const int t = threadIdx.x, wid = t >> 6, lane = t & 63;
  const int m0 = blockIdx.y * 64, n0 = blockIdx.x * 128;
  const int wn = wid * 32;

  fx4 acc[4][2];
  #pragma unroll
  for (int a = 0; a < 4; a++)
    #pragma unroll
    for (int b = 0; b < 2; b++)
      #pragma unroll
      for (int i = 0; i < 4; i++) acc[a][b][i] = 0.f;

  const int rA = t >> 2, kpA = (t & 3) << 3;
  const int rW = t >> 1, kpW = (t & 1) << 4;
  const int row = lane & 15, kq = lane >> 4;

  for (int kt = 0; kt < D; kt += 32){
    *(bf16x8*)&sAh[rA * BKp + kpA] = *(const bf16x8*)(Ah + (size_t)(m0 + rA) * D + kt + kpA);
    *(bf16x8*)&sAl[rA * BKp + kpA] = *(const bf16x8*)(Al + (size_t)(m0 + rA) * D + kt + kpA);
    *(bf16x8*)&sWh[rW * BKp + kpW]     = *(const bf16x8*)(Wh + (size_t)(n0 + rW) * D + kt + kpW);
    *(bf16x8*)&sWh[rW * BKp + kpW + 8] = *(const bf16x8*)(Wh + (size_t)(n0 + rW) * D + kt + kpW + 8);
    *(bf16x8*)&sWl[rW * BKp + kpW]     = *(const bf16x8*)(Wl + (size_t)(n0 + rW) * D + kt + kpW);
    *(bf16x8*)&sWl[rW * BKp + kpW + 8] = *(const bf16x8*)(Wl + (size_t)(n0 + rW) * D + kt + kpW + 8);
    __syncthreads();
    bf16x8 ah[4], al[4], bh[2], bl[2];
    #pragma unroll
    for (int tm = 0; tm < 4; tm++){
      ah[tm] = *(const bf16x8*)&sAh[(tm * 16 + row) * BKp + kq * 8];
      al[tm] = *(const bf16x8*)&sAl[(tm * 16 + row) * BKp + kq * 8];
    }
    #pragma unroll
    for (int tn = 0; tn < 2; tn++){
      bh[tn] = *(const bf16x8*)&sWh[(wn + tn * 16 + row) * BKp + kq * 8];
      bl[tn] = *(const bf16x8*)&sWl[(wn + tn * 16 + row) * BKp + kq * 8];
    }
    #pragma unroll
    for (int tm = 0; tm < 4; tm++)
      #pragma unroll
      for (int tn = 0; tn < 2; tn++){
        acc[tm][tn] = __builtin_amdgcn_mfma_f32_16x16x32_bf16(ah[tm], bh[tn], acc[tm][tn], 0, 0, 0);
        acc[tm][tn] = __builtin_amdgcn_mfma_f32_16x16x32_bf16(ah[tm], bl[tn], acc[tm][tn], 0, 0, 0);
        acc[tm][tn] = __builtin_amdgcn_mfma_f32_16x16x32_bf16(al[tm], bh[tn], acc[tm][tn], 0, 0, 0);
      }
    __syncthreads();
  }

  const int row4 = (lane >> 4) * 4, coln = lane & 15;
  #pragma unroll
  for (int tm = 0; tm < 4; tm++)
    #pragma unroll
    for (int tn = 0; tn < 2; tn++){
      int n = n0 + wn + tn * 16 + coln;
      int mb = m0 + tm * 16 + row4;
      float4 v4;
      float* vp = (float*)&v4;
      #pragma unroll
      for (int i = 0; i < 4; i++) vp[i] = acc[tm][tn][i] + bias[n];
      if (n < E){
        *(float4*)&C[(size_t)n * M + mb] = v4;          // xmT transposed
      } else {
        #pragma unroll
        for (int i = 0; i < 4; i++){
          float sig = 1.f / (1.f + expf(-vp[i]));
          vp[i] = vp[i] * sig;
        }
        *(float4*)&C2[(size_t)(n - E) * M + mb] = v4;   // zst transposed
      }
    }
}

// ---------------- patch MFMA GEMM 64x64 (pre-split A, +pos epilogue) ----------------
__global__ __launch_bounds__(256)
void gemm_patch(const short* __restrict__ Ah, const short* __restrict__ Al,
                const float* __restrict__ bias, float* __restrict__ C,
                const float* __restrict__ pos){
  constexpr int BKp = 40;
  __shared__ __align__(16) short sAh[64 * BKp], sAl[64 * BKp];
  __shared__ __align__(16) short sWh[64 * BKp], sWl[64 * BKp];
  const int t = threadIdx.x, wid = t >> 6, lane = t & 63;
  const int m0 = blockIdx.y * 64, n0 = blockIdx.x * 64;

  fx4 acc[4];
  #pragma unroll
  for (int a = 0; a < 4; a++)
    #pragma unroll
    for (int i = 0; i < 4; i++) acc[a][i] = 0.f;

  const int r = t >> 2, kp = (t & 3) << 3;
  const int row = lane & 15, kq = lane >> 4;

  for (int kt = 0; kt < 768; kt += 32){
    *(bf16x8*)&sAh[r * BKp + kp] = *(const bf16x8*)(Ah + (size_t)(m0 + r) * 768 + kt + kp);
    *(bf16x8*)&sAl[r * BKp + kp] = *(const bf16x8*)(Al + (size_t)(m0 + r) * 768 + kt + kp);
    *(bf16x8*)&sWh[r * BKp + kp] = *(const bf16x8*)(g_pw_h + (size_t)(n0 + r) * 768 + kt + kp);
    *(bf16x8*)&sWl[r * BKp + kp] = *(const bf16x8*)(g_pw_l + (size_t)(n0 + r) * 768 + kt + kp);
    __syncthreads();
    bf16x8 bh = *(const bf16x8*)&sWh[(wid * 16 + row) * BKp + kq * 8];
    bf16x8 bl = *(const bf16x8*)&sWl[(wid * 16 + row) * BKp + kq * 8];
    #pragma unroll
    for (int tm = 0; tm < 4; tm++){
      bf16x8 ah = *(const bf16x8*)&sAh[(tm * 16 + row) * BKp + kq * 8];
      bf16x8 al = *(const bf16x8*)&sAl[(tm * 16 + row) * BKp + kq * 8];
      acc[tm] = __builtin_amdgcn_mfma_f32_16x16x32_bf16(ah, bh, acc[tm], 0, 0, 0);
      acc[tm] = __builtin_amdgcn_mfma_f32_16x16x32_bf16(ah, bl, acc[tm], 0, 0, 0);
      acc[tm] = __builtin_amdgcn_mfma_f32_16x16x32_bf16(al, bh, acc[tm], 0, 0, 0);
    }
    __syncthreads();
  }

  const int row4 = (lane >> 4) * 4, coln = lane & 15;
  #pragma unroll
  for (int tm = 0; tm < 4; tm++){
    int n = n0 + wid * 16 + coln;
    int mb = m0 + tm * 16 + row4;
    #pragma unroll
    for (int i = 0; i < 4; i++){
      int m = mb + i;
      C[(size_t)m * D + n] = acc[tm][i] + bias[n] + pos[(size_t)(m & (Np - 1)) * D + n];
    }
  }
}

// ---------------- scale MFMA GEMM 64x64: A = f32 x, hi/lo converted in staging ----------------
__global__ __launch_bounds__(256)
void gemm_scale(const float* __restrict__ A, size_t woff,
                const float* __restrict__ bias, float* __restrict__ C){
  constexpr int BKp = 40;
  __shared__ __align__(16) short sAh[64 * BKp], sAl[64 * BKp];
  __shared__ __align__(16) short sWh[64 * BKp], sWl[64 * BKp];
  const short* Wh = g_swx_h + woff;
  const short* Wl = g_swx_l + woff;
  const int t = threadIdx.x, wid = t >> 6, lane = t & 63;
  const int m0 = blockIdx.y * 64, n0 = blockIdx.x * 64;

  fx4 acc[4];
  #pragma unroll
  for (int a = 0; a < 4; a++)
    #pragma unroll
    for (int i = 0; i < 4; i++) acc[a][i] = 0.f;

  const int r = t >> 2, kp = (t & 3) << 3;
  const int row = lane & 15, kq = lane >> 4;

  for (int kt = 0; kt < D; kt += 32){
    {
      const float* ap = A + (size_t)(m0 + r) * D + kt + kp;
      float4 f0 = *(const float4*)ap, f1 = *(const float4*)(ap + 4);
      float f[8] = {f0.x, f0.y, f0.z, f0.w, f1.x, f1.y, f1.z, f1.w};
      short hh[8], ll[8];
      #pragma unroll
      for (int i = 0; i < 8; i++){
        unsigned short h = f2bf(f[i]);
        hh[i] = (short)h; ll[i] = (short)f2bf(f[i] - bf2f(h));
      }
      *(bf16x8*)&sAh[r * BKp + kp] = *(bf16x8*)hh;
      *(bf16x8*)&sAl[r * BKp + kp] = *(bf16x8*)ll;
    }
    *(bf16x8*)&sWh[r * BKp + kp] = *(const bf16x8*)(Wh + (size_t)(n0 + r) * D + kt + kp);
    *(bf16x8*)&sWl[r * BKp + kp] = *(const bf16x8*)(Wl + (size_t)(n0 + r) * D + kt + kp);
    __syncthreads();
    bf16x8 bh = *(const bf16x8*)&sWh[(wid * 16 + row) * BKp + kq * 8];
    bf16x8 bl = *(const bf16x8*)&sWl[(wid * 16 + row) * BKp + kq * 8];
    #pragma unroll
    for (int tm = 0; tm < 4; tm++){
      bf16x8 ah = *(const bf16x8*)&sAh[(tm * 16 + row) * BKp + kq * 8];
      bf16x8 al = *(const bf16x8*)&sAl[(tm * 16 + row) * BKp + kq * 8];
      acc[tm] = __builtin_amdgcn_mfma_f32_16x16x32_bf16(ah, bh, acc[tm], 0, 0, 0);
      acc[tm] = __builtin_amdgcn_mfma_f32_16x16x32_bf16(ah, bl, acc[tm], 0, 0, 0);
      acc[tm] = __builtin_amdgcn_mfma_f32_16x16x32_bf16(al, bh, acc[tm], 0, 0, 0);
    }
    __syncthreads();
  }

  const int row4 = (lane >> 4) * 4, coln = lane & 15;
  #pragma unroll
  for (int tm = 0; tm < 4; tm++){
    int n = n0 + wid * 16 + coln;
    int mb = m0 + tm * 16 + row4;
    #pragma unroll
    for (int i = 0; i < 4; i++){
      int m = mb + i;
      C[(size_t)m * D + n] = acc[tm][i] + bias[n];
    }
  }
}

// ---------------- out-proj MFMA GEMM, TRANSPOSED A; epilogue: residual add + zero xBC ----------------
__global__ __launch_bounds__(256)
void gemm_bf_at(const short* __restrict__ ATh, const short* __restrict__ ATl, int K,
                size_t woff, const float* __restrict__ bias,
                float* __restrict__ C, int ncols, float* __restrict__ zbuf){
  constexpr int BKp = 40;
  __shared__ __align__(16) short sAh[64 * BKp], sAl[64 * BKp];
  __shared__ __align__(16) short sWh[64 * BKp], sWl[64 * BKp];
  const short* Wh = g_ow_h + woff;
  const short* Wl = g_ow_l + woff;
  const int t = threadIdx.x, wid = t >> 6, lane = t & 63;
  const int m0 = blockIdx.y * 64, n0 = blockIdx.x * 64;

  fx4 acc[4];
  #pragma unroll
  for (int a = 0; a < 4; a++)
    #pragma unroll
    for (int i = 0; i < 4; i++) acc[a][i] = 0.f;

  const int rw = t >> 2, kpw = (t & 3) << 3;
  const int kr2 = (t & 15) * 2, mc4 = (t >> 4) * 4;
  const int row = lane & 15, kq = lane >> 4;

  for (int kt = 0; kt < K; kt += 32){
    {
      const uint2 h0 = *(const uint2*)(ATh + (size_t)(kt + kr2) * M + m0 + mc4);
      const uint2 h1 = *(const uint2*)(ATh + (size_t)(kt + kr2 + 1) * M + m0 + mc4);
      const uint2 l0 = *(const uint2*)(ATl + (size_t)(kt + kr2) * M + m0 + mc4);
      const uint2 l1 = *(const uint2*)(ATl + (size_t)(kt + kr2 + 1) * M + m0 + mc4);
      const unsigned int h0a[2] = {h0.x, h0.y}, h1a[2] = {h1.x, h1.y};
      const unsigned int l0a[2] = {l0.x, l0.y}, l1a[2] = {l1.x, l1.y};
      #pragma unroll
      for (int j = 0; j < 4; j++){
        unsigned int s0 = (h0a[j >> 1] >> ((j & 1) * 16)) & 0xFFFFu;
        unsigned int s1 = (h1a[j >> 1] >> ((j & 1) * 16)) & 0xFFFFu;
        *(unsigned int*)&sAh[(mc4 + j) * BKp + kr2] = s0 | (s1 << 16);
        unsigned int t0 = (l0a[j >> 1] >> ((j & 1) * 16)) & 0xFFFFu;
        unsigned int t1 = (l1a[j >> 1] >> ((j & 1) * 16)) & 0xFFFFu;
        *(unsigned int*)&sAl[(mc4 + j) * BKp + kr2] = t0 | (t1 << 16);
      }
    }
    *(bf16x8*)&sWh[rw * BKp + kpw] = *(const bf16x8*)(Wh + (size_t)(n0 + rw) * K + kt + kpw);
    *(bf16x8*)&sWl[rw * BKp + kpw] = *(const bf16x8*)(Wl + (size_t)(n0 + rw) * K + kt + kpw);
    __syncthreads();
    bf16x8 bh = *(const bf16x8*)&sWh[(wid * 16 + row) * BKp + kq * 8];
    bf16x8 bl = *(const bf16x8*)&sWl[(wid * 16 + row) * BKp + kq * 8];
    #pragma unroll
    for (int tm = 0; tm < 4; tm++){
      bf16x8 ah = *(const bf16x8*)&sAh[(tm * 16 + row) * BKp + kq * 8];
      bf16x8 al = *(const bf16x8*)&sAl[(tm * 16 + row) * BKp + kq * 8];
      acc[tm] = __builtin_amdgcn_mfma_f32_16x16x32_bf16(ah, bh, acc[tm], 0, 0, 0);
      acc[tm] = __builtin_amdgcn_mfma_f32_16x16x32_bf16(ah, bl, acc[tm], 0, 0, 0);
      acc[tm] = __builtin_amdgcn_mfma_f32_16x16x32_bf16(al, bh, acc[tm], 0, 0, 0);
    }
    __syncthreads();
  }

  const int row4 = (lane >> 4) * 4, coln = lane & 15;
  #pragma unroll
  for (int tm = 0; tm < 4; tm++)
    #pragma unroll
    for (int i = 0; i < 4; i++){
      int m = m0 + tm * 16 + row4 + i;
      int n = n0 + wid * 16 + coln;
      float v = acc[tm][i] + bias[n] + C[(size_t)m * ncols + n];
      C[(size_t)m * ncols + n] = v;
    }

  // zero xBC for next layer's xp accumulation (stream order guarantees visibility)
  int gid = blockIdx.y * gridDim.x + blockIdx.x;
  int idx = gid * 256 + t;
  if (idx < M * 16)
    *(float2*)&zbuf[idx * 2] = make_float2(0.f, 0.f);
}

// ---------------- xp GEMM (K-split x4, atomic): xBC [m][xB(16)|xC(16)] ----------------
__global__ __launch_bounds__(256)
void gemm_xp(const float* __restrict__ xcT, const float* __restrict__ W,
             const float* __restrict__ bias, float* __restrict__ C){
  __shared__ float As[16][64 + 1];
  __shared__ float Ws[16][32 + 1];
  int tid = threadIdx.x;
  int tx = tid & 15, ty = tid >> 4;
  int m0 = blockIdx.y * 64, kb = blockIdx.x * 192;
  float acc[4][2];
  #pragma unroll
  for (int i = 0; i < 4; i++){ acc[i][0] = 0.f; acc[i][1] = 0.f; }
  for (int kt = kb; kt < kb + 192; kt += 16){
    #pragma unroll
    for (int ps = 0; ps < 4; ps++){
      int rr = (tid >> 6) + 4 * ps, mc = tid & 63;
      As[rr][mc] = xcT[(size_t)(kt + rr) * M + m0 + mc];
    }
    if (tid < 128){
      int c = tid >> 2, kk = (tid & 3) << 2;
      const float* wp = W + (size_t)c * E + kt + kk;
      Ws[kk + 0][c] = wp[0]; Ws[kk + 1][c] = wp[1];
      Ws[kk + 2][c] = wp[2]; Ws[kk + 3][c] = wp[3];
    }
    __syncthreads();
    #pragma unroll
    for (int k = 0; k < 16; k++){
      float a[4], w[2];
      #pragma unroll
      for (int i = 0; i < 4; i++) a[i] = As[k][ty * 4 + i];
      w[0] = Ws[k][tx * 2]; w[1] = Ws[k][tx * 2 + 1];
      #pragma unroll
      for (int i = 0; i < 4; i++){ acc[i][0] += a[i] * w[0]; acc[i][1] += a[i] * w[1]; }
    }
    __syncthreads();
  }
  #pragma unroll
  for (int i = 0; i < 4; i++){
    int m = m0 + ty * 4 + i;
    #pragma unroll
    for (int j = 0; j < 2; j++){
      int n = tx * 2 + j;
      float v = acc[i][j];
      if (blockIdx.x == 0) v += bias[n];
      atomicAdd(&C[(size_t)m * 32 + n], v);
    }
  }
}

// ---------------- depthwise causal conv (K=4) + SiLU on transposed layout ----------------
__global__ __launch_bounds__(256)
void conv_silu_t(const float* __restrict__ xmT, const float* __restrict__ cw,
                 const float* __restrict__ cb, float* __restrict__ xcT){
  const int e = blockIdx.x, t = threadIdx.x;
  const float w0 = cw[e * 4], w1 = cw[e * 4 + 1], w2 = cw[e * 4 + 2], w3 = cw[e * 4 + 3];
  const float bias = cb[e];
  const float* src = xmT + (size_t)e * M;
  float* dst = xcT + (size_t)e * M;
  int mb = t * 8;
  #pragma unroll
  for (int j = 0; j < 8; j++){
    int m = mb + j, n = m & (Np - 1);
    float acc = bias + w3 * src[m];
    if (n >= 1) acc += w2 * src[m - 1];
    if (n >= 2) acc += w1 * src[m - 2];
    if (n >= 3) acc += w0 * src[m - 3];
    float sig = 1.f / (1.f + expf(-acc));
    dst[m] = acc * sig;
  }
}

// ---------------- chunked selective scan: fused dt (R13 body), unpacked xBC ----------------
// dt in [1e-4,1], A in [-16,-1] => dt*a in [-16,-1e-4]; ref's [-20,0] clip can't fire.
__global__ __launch_bounds__(256)
void scan_kernel(const float* __restrict__ xcT, const float* __restrict__ zst,
                 const float* __restrict__ xBC,
                 const float* __restrict__ Aptr, const float* __restrict__ Dp,
                 const float* __restrict__ dt_w, const float* __restrict__ dt_b,
                 short* __restrict__ yh, short* __restrict__ yl){
  __shared__ float yloc[16 * 65];
  __shared__ float sdt[64 * 17], sxc[64 * 17];
  __shared__ float hloc[16][16], prodA[16][16], Hin[16][16];
  const int t = threadIdx.x, g = t >> 4, s = t & 15;
  const int r = blockIdx.x, b = r / E, e = r % E;
  const float a   = Aptr[e * S + s];
  const float dpe = Dp[e];
  const float* xcp = xcT + (size_t)e * M + b * Np;
  const float* zsp = zst + (size_t)e * M + b * Np;
  const int bNp = b * Np;

  { // preload: dt[n] = clip(softplus(xBC[n,0:16].dt_w[e] + dt_b[e])), stage xc
    const float* dw = dt_w + e * 16;
    float4 w0 = *(const float4*)dw,       w1 = *(const float4*)(dw + 4);
    float4 w2 = *(const float4*)(dw + 8), w3 = *(const float4*)(dw + 12);
    float db = dt_b[e];
    #pragma unroll
    for (int q = t; q < 1024; q += 256){
      const float* xb = xBC + (size_t)(bNp + q) * 32;
      float4 a0 = *(const float4*)xb,       a1 = *(const float4*)(xb + 4);
      float4 a2 = *(const float4*)(xb + 8), a3 = *(const float4*)(xb + 12);
      float v = db + a0.x * w0.x + a0.y * w0.y + a0.z * w0.z + a0.w * w0.w
                   + a1.x * w1.x + a1.y * w1.y + a1.z * w1.z + a1.w * w1.w
                   + a2.x * w2.x + a2.y * w2.y + a2.z * w2.z + a2.w * w2.w
                   + a3.x * w3.x + a3.y * w3.y + a3.z * w3.z + a3.w * w3.w;
      v = (v > 15.f) ? v : log1pf(expf(v));
      v = fminf(fmaxf(v, 1e-4f), 1.0f);
      sdt[(q & 63) * 17 + (q >> 6)] = v;
      sxc[(q & 63) * 17 + (q >> 6)] = xcp[q];
    }
  }
  __syncthreads();

  const int n0 = g * 64;
  const int mbase = bNp + n0;

  float h = 0.f, P = 1.f;
  #pragma unroll 8
  for (int i = 0; i < 64; i++){
    int m = mbase + i;
    float dt  = sdt[i * 17 + g];
    float xcv = sxc[i * 17 + g];
    float xb  = xBC[(size_t)m * 32 + s];
    float xcs = xBC[(size_t)m * 32 + 16 + s];
    float dA = __expf(dt * a);
    h = dA * h + xb * xcv;
    P *= dA;
    float p = row_sum16(h * xcs);
    if (s == 0) yloc[g * 65 + i] = p + dpe * xcv;
  }
  hloc[g][s] = h; prodA[g][s] = P;
  __syncthreads();
  if (t < 16){
    float H = 0.f;
    #pragma unroll
    for (int g2 = 0; g2 < 16; g2++){
      Hin[g2][t] = H;
      H = prodA[g2][t] * H + hloc[g2][t];
    }
  }
  __syncthreads();
  float Q = Hin[g][s];
  #pragma unroll 8
  for (int i = 0; i < 64; i++){
    int m = mbase + i;
    float dt  = sdt[i * 17 + g];
    float xcs = xBC[(size_t)m * 32 + 16 + s];
    float dA = __expf(dt * a);
    Q *= dA;
    float p = row_sum16(Q * xcs);
    if (s == 0) yloc[g * 65 + i] += p;
  }
  __syncthreads();

  { // coalesced hi/lo bf16 write, [e][m] layout
    int n4 = t * 4;
    float4 z4 = *(const float4*)&zsp[n4];
    const float* zp = (const float*)&z4;
    int gy = n4 >> 6, iy = n4 & 63;
    unsigned int hpack[2], lpack[2];
    #pragma unroll
    for (int half = 0; half < 2; half++){
      unsigned int hp = 0, lp = 0;
      #pragma unroll
      for (int j = 0; j < 2; j++){
        float val = yloc[gy * 65 + iy + half * 2 + j] * zp[half * 2 + j];
        unsigned short hh = f2bf(val);
        unsigned short ll = f2bf(val - bf2f(hh));
        hp |= ((unsigned int)hh) << (16 * j);
        lp |= ((unsigned int)ll) << (16 * j);
      }
      hpack[half] = hp; lpack[half] = lp;
    }
    size_t o = (size_t)e * M + bNp + n4;
    *(uint2*)&yh[o] = make_uint2(hpack[0], hpack[1]);
    *(uint2*)&yl[o] = make_uint2(lpack[0], lpack[1]);
  }
}

extern "C" void kernel_launch(void* const* d_in, const int* in_sizes, int n_in,
                              void* d_out, int out_size, void* d_ws, size_t ws_size,
                              hipStream_t stream){
  const float* px      = (const float*)d_in[0];
  const float* patch_w = (const float*)d_in[1];
  const float* patch_b = (const float*)d_in[2];
  const float* pos     = (const float*)d_in[3];
  const float* norm_w  = (const float*)d_in[4];
  const float* norm_b  = (const float*)d_in[5];
  const float* in_w    = (const float*)d_in[6];
  const float* in_b    = (const float*)d_in[7];
  const float* conv_w  = (const float*)d_in[8];
  const float* conv_b  = (const float*)d_in[9];
  const float* xp_w    = (const float*)d_in[10];
  const float* xp_b    = (const float*)d_in[11];
  const float* dt_w    = (const float*)d_in[12];
  const float* dt_b    = (const float*)d_in[13];
  const float* Aab     = (const float*)d_in[14];
  const float* Dp      = (const float*)d_in[15];
  const float* out_w   = (const float*)d_in[16];
  const float* out_b   = (const float*)d_in[17];
  const float* fnorm_w = (const float*)d_in[18];
  const float* fnorm_b = (const float*)d_in[19];
  const float* scale_w = (const float*)d_in[20];
  const float* scale_b = (const float*)d_in[21];
  float* out = (float*)d_out;

  // workspace
  float* x   = (float*)d_ws;                  // M*D
  float* xmT = x + (size_t)M * D;             // E*M f32 (transposed x_main)
  float* zst = xmT + (size_t)M * E;           // E*M
  float* xcT = zst + (size_t)M * E;           // E*M
  float* xBC = xcT + (size_t)M * E;           // M*32 ([xB|xC] halves)
  short* xnh = (short*)(xBC + (size_t)M * 32);// M*D
  short* xnl = xnh + (size_t)M * D;           // M*D
  short* yh  = (short*)xmT;                   // E*M shorts (alias: dead x_main)
  short* yl  = yh + (size_t)M * E;
  short* pbh = yh, *pbl = yl;                 // patch buffer alias

  constexpr size_t TOTW = PW_N + IW_N + OW_N + SW_N;
  convw_kernel<<<(int)((TOTW + 255) / 256), 256, 0, stream>>>(patch_w, in_w, out_w, scale_w);
  hipMemsetAsync(xBC, 0, (size_t)M * 32 * sizeof(float), stream);   // layer-0 init

  patchify_kernel<<<(M * 768 + 255) / 256, 256, 0, stream>>>(px, pbh, pbl);
  gemm_patch<<<dim3(D / 64, M / 64), 256, 0, stream>>>(pbh, pbl, patch_b, x, pos);

  for (int l = 0; l < L; l++){
    layernorm_bf<<<M / 4, 256, 0, stream>>>(x, norm_w + l * D, norm_b + l * D, xnh, xnl);
    gemm_in<<<dim3(TWO_E / 128, M / 64), 256, 0, stream>>>(
        xnh, xnl, (size_t)l * TWO_E * D, in_b + l * TWO_E, xmT, zst);
    conv_silu_t<<<E, 256, 0, stream>>>(
        xmT, conv_w + (size_t)l * E * 4, conv_b + l * E, xcT);
    gemm_xp<<<dim3(4, M / 64), 256, 0, stream>>>(
        xcT, xp_w + (size_t)l * 32 * E, xp_b + l * 32, xBC);
    scan_kernel<<<Bz * E, 256, 0, stream>>>(
        xcT, zst, xBC, Aab + (size_t)l * E * S, Dp + l * E,
        dt_w + (size_t)l * E * S, dt_b + l * E, yh, yl);
    gemm_bf_at<<<dim3(D / 64, M / 64), 256, 0, stream>>>(
        yh, yl, E, (size_t)l * D * E, out_b + l * D, x, D, xBC);
    if (l % 4 == 0 && l / 4 < 3){
      int j = l / 4;
      gemm_scale<<<dim3(D / 64, M / 64), 256, 0, stream>>>(
          x, (size_t)j * D * D, scale_b + j * D, out + (size_t)(1 + j) * M * D);
    }
  }
  layernorm_f32<<<M / 4, 256, 0, stream>>>(x, fnorm_w, fnorm_b, out);
}